// Round 1
// baseline (1441.882 us; speedup 1.0000x reference)
//
#include <hip/hip_runtime.h>
#include <cstddef>

// Problem constants
#define BB 16
#define LL 2048
#define DM 128
#define DI 256
#define DS 16
#define DTR 8
#define MP (BB*LL)          // 32768 positions
#define NSEG 64             // scan segments
#define SEGLEN (LL/NSEG)    // 32 steps per segment

// ---------------------------------------------------------------------------
// Generic fp32 GEMM: C[M,N] (+)= A[M,K] @ W[N,K]^T (+ bias[n])
// 64x64 tile, BK=16, 256 threads, 4x4 per thread.
// ---------------------------------------------------------------------------
template<int ACCUM>
__global__ __launch_bounds__(256) void gemm_nt(const float* __restrict__ A,
    const float* __restrict__ W, const float* __restrict__ bias,
    float* __restrict__ C, int M, int N, int K) {
  __shared__ float As[16][68];
  __shared__ float Ws[16][68];
  int tid = threadIdx.x;
  int m0 = blockIdx.x * 64, n0 = blockIdx.y * 64;
  int tx = tid & 15, ty = tid >> 4;
  float acc[4][4] = {};
  for (int k0 = 0; k0 < K; k0 += 16) {
#pragma unroll
    for (int i = 0; i < 4; i++) {
      int idx = tid + i * 256;
      int mm = idx >> 4, kk = idx & 15;
      int gk = k0 + kk;
      int gm = m0 + mm;
      As[kk][mm] = (gk < K && gm < M) ? A[(size_t)gm * K + gk] : 0.f;
      int gn = n0 + mm;
      Ws[kk][mm] = (gk < K && gn < N) ? W[(size_t)gn * K + gk] : 0.f;
    }
    __syncthreads();
#pragma unroll
    for (int kk = 0; kk < 16; kk++) {
      float4 av = *(const float4*)(&As[kk][ty * 4]);
      float4 wv = *(const float4*)(&Ws[kk][tx * 4]);
      float aa[4] = {av.x, av.y, av.z, av.w};
      float ww[4] = {wv.x, wv.y, wv.z, wv.w};
#pragma unroll
      for (int i = 0; i < 4; i++)
#pragma unroll
        for (int j = 0; j < 4; j++)
          acc[i][j] += aa[i] * ww[j];
    }
    __syncthreads();
  }
#pragma unroll
  for (int i = 0; i < 4; i++) {
    int gm = m0 + ty * 4 + i;
    if (gm >= M) continue;
#pragma unroll
    for (int j = 0; j < 4; j++) {
      int gn = n0 + tx * 4 + j;
      if (gn >= N) continue;
      float v = acc[i][j];
      if (bias) v += bias[gn];
      if (ACCUM) C[(size_t)gm * N + gn] += v;
      else       C[(size_t)gm * N + gn] = v;
    }
  }
}

// ---------------------------------------------------------------------------
// RMSNorm over last dim (=128). One wave per position, 4 positions per block.
// ---------------------------------------------------------------------------
__global__ __launch_bounds__(256) void rmsnorm_kernel(const float* __restrict__ x,
    const float* __restrict__ w, float* __restrict__ o) {
  int lane = threadIdx.x & 63;
  int pos = blockIdx.x * 4 + (threadIdx.x >> 6);
  const float* row = x + (size_t)pos * DM;
  float v0 = row[lane], v1 = row[lane + 64];
  float ss = v0 * v0 + v1 * v1;
#pragma unroll
  for (int off = 1; off < 64; off <<= 1) ss += __shfl_xor(ss, off);
  float sc = rsqrtf(ss * (1.f / DM) + 1e-5f);
  o[(size_t)pos * DM + lane]      = v0 * sc * w[lane];
  o[(size_t)pos * DM + lane + 64] = v1 * sc * w[lane + 64];
}

// ---------------------------------------------------------------------------
// Causal depthwise conv (k=4) + bias + SiLU. One thread per (pos, d).
// ---------------------------------------------------------------------------
__global__ __launch_bounds__(256) void conv_silu_kernel(const float* __restrict__ xm,
    const float* __restrict__ cw, const float* __restrict__ cb,
    float* __restrict__ xc) {
  int idx = blockIdx.x * 256 + threadIdx.x;   // pos*256 + d
  int d = idx & 255;
  int pos = idx >> 8;
  int l = pos & (LL - 1);
  float w0 = cw[d * 4], w1 = cw[d * 4 + 1], w2 = cw[d * 4 + 2], w3 = cw[d * 4 + 3];
  float acc = cb[d] + w3 * xm[idx];
  if (l > 0) acc += w2 * xm[idx - 256];
  if (l > 1) acc += w1 * xm[idx - 512];
  if (l > 2) acc += w0 * xm[idx - 768];
  xc[idx] = acc / (1.f + __expf(-acc));
}

// ---------------------------------------------------------------------------
// dt_proj (K=8) + softplus -> delta. One thread per (pos, d); block = one pos.
// ---------------------------------------------------------------------------
__global__ __launch_bounds__(256) void dtproj_kernel(const float* __restrict__ xdbl,
    const float* __restrict__ dtw, const float* __restrict__ dtb,
    float* __restrict__ delta) {
  int idx = blockIdx.x * 256 + threadIdx.x;
  int d = idx & 255;
  int pos = idx >> 8;
  const float* r = xdbl + (size_t)pos * 40;
  float acc = dtb[d];
#pragma unroll
  for (int j = 0; j < 8; j++) acc += r[j] * dtw[d * 8 + j];
  delta[idx] = fmaxf(acc, 0.f) + log1pf(__expf(-fabsf(acc)));
}

// ---------------------------------------------------------------------------
// Segmented selective scan. Thread = one (b, d), holds all 16 states in regs.
// Phase 1: local scan from h=0 over a 32-step segment; store (prod dA, h_final).
// Combine: chain segment boundaries (scan over 64 segments per (b,d,n)).
// Phase 2: replay with correct initial state; y = (sum_n h*C + u*D)*silu(z).
// seg buffers layout: elem (s,b,d,n) at (s*4096 + b*256 + d)*16 + n
// ---------------------------------------------------------------------------
__global__ __launch_bounds__(256) void scan_phase1(const float* __restrict__ delta,
    const float* __restrict__ xc, const float* __restrict__ xdbl,
    const float* __restrict__ A_log, float* __restrict__ sega,
    float* __restrict__ segh) {
  int s = blockIdx.x, b = blockIdx.y, d = threadIdx.x;
  float Ad[DS], h[DS], ap[DS];
#pragma unroll
  for (int n = 0; n < DS; n++) {
    Ad[n] = -__expf(A_log[d * DS + n]);
    h[n] = 0.f;
    ap[n] = 1.f;
  }
  size_t base = (size_t)b * LL + s * SEGLEN;
  for (int t = 0; t < SEGLEN; t++) {
    size_t p = base + t;
    float dl = delta[p * 256 + d];
    float u  = xc[p * 256 + d];
    const float* Bp = xdbl + p * 40 + 8;
    float du = dl * u;
#pragma unroll
    for (int n = 0; n < DS; n++) {
      float dA = __expf(dl * Ad[n]);
      h[n] = dA * h[n] + du * Bp[n];
      ap[n] *= dA;
    }
  }
  size_t o = ((size_t)s * 4096 + b * 256 + d) * DS;
#pragma unroll
  for (int n = 0; n < DS; n++) { sega[o + n] = ap[n]; segh[o + n] = h[n]; }
}

__global__ __launch_bounds__(256) void scan_combine(float* __restrict__ sega,
    const float* __restrict__ segh) {
  int idx = blockIdx.x * 256 + threadIdx.x;  // (b*256+d)*16+n, 65536 total
  float h0 = 0.f;
  for (int s = 0; s < NSEG; s++) {
    size_t q = (size_t)s * 65536 + idx;
    float a = sega[q], hh = segh[q];
    sega[q] = h0;            // becomes the segment's initial state
    h0 = a * h0 + hh;
  }
}

__global__ __launch_bounds__(256) void scan_phase2(const float* __restrict__ delta,
    const float* __restrict__ xc, const float* __restrict__ xdbl,
    const float* __restrict__ z, const float* __restrict__ A_log,
    const float* __restrict__ Dp, const float* __restrict__ sega,
    float* __restrict__ y) {
  int s = blockIdx.x, b = blockIdx.y, d = threadIdx.x;
  float Ad[DS], h[DS];
  size_t o = ((size_t)s * 4096 + b * 256 + d) * DS;
#pragma unroll
  for (int n = 0; n < DS; n++) {
    Ad[n] = -__expf(A_log[d * DS + n]);
    h[n] = sega[o + n];
  }
  float Dd = Dp[d];
  size_t base = (size_t)b * LL + s * SEGLEN;
  for (int t = 0; t < SEGLEN; t++) {
    size_t p = base + t;
    float dl = delta[p * 256 + d];
    float u  = xc[p * 256 + d];
    const float* Bp = xdbl + p * 40 + 8;
    const float* Cp = xdbl + p * 40 + 24;
    float du = dl * u;
    float acc = 0.f;
#pragma unroll
    for (int n = 0; n < DS; n++) {
      float dA = __expf(dl * Ad[n]);
      h[n] = dA * h[n] + du * Bp[n];
      acc += h[n] * Cp[n];
    }
    float zv = z[p * 256 + d];
    float sig = 1.f / (1.f + __expf(-zv));
    y[p * 256 + d] = (acc + u * Dd) * (zv * sig);
  }
}

// ---------------------------------------------------------------------------
// Final pooling + classifier
// ---------------------------------------------------------------------------
__global__ void zero_kernel(float* __restrict__ p, int n) {
  int i = blockIdx.x * 256 + threadIdx.x;
  if (i < n) p[i] = 0.f;
}

__global__ __launch_bounds__(256) void pool_kernel(const float* __restrict__ xn,
    float* __restrict__ pooled) {
  int b = blockIdx.x, chunk = blockIdx.y;
  int d = threadIdx.x & 127, lh = threadIdx.x >> 7;
  float s = 0.f;
  size_t base = (size_t)b * LL + chunk * 256 + lh * 128;
  for (int i = 0; i < 128; i++) s += xn[(base + i) * DM + d];
  atomicAdd(&pooled[b * DM + d], s * (1.f / LL));
}

__global__ void cls_kernel(const float* __restrict__ pooled,
    const float* __restrict__ cw, const float* __restrict__ cb,
    float* __restrict__ out) {
  int t = threadIdx.x;
  if (t < 80) {
    int b = t / 5, c = t % 5;
    float acc = cb[c];
    for (int d = 0; d < DM; d++) acc += pooled[b * DM + d] * cw[c * DM + d];
    out[t] = acc;
  }
}

// ---------------------------------------------------------------------------
extern "C" void kernel_launch(void* const* d_in, const int* in_sizes, int n_in,
                              void* d_out, int out_size, void* d_ws, size_t ws_size,
                              hipStream_t stream) {
  const float* x         = (const float*)d_in[0];
  const float* enc_w     = (const float*)d_in[1];
  const float* enc_b     = (const float*)d_in[2];
  const float* norm_w    = (const float*)d_in[3];
  const float* in_proj_w = (const float*)d_in[4];
  const float* conv_w    = (const float*)d_in[5];
  const float* conv_b    = (const float*)d_in[6];
  const float* x_proj_w  = (const float*)d_in[7];
  const float* dt_proj_w = (const float*)d_in[8];
  const float* dt_proj_b = (const float*)d_in[9];
  const float* A_log     = (const float*)d_in[10];
  const float* Dp        = (const float*)d_in[11];
  const float* out_proj_w= (const float*)d_in[12];
  const float* norm_f_w  = (const float*)d_in[13];
  const float* cls_w     = (const float*)d_in[14];
  const float* cls_b     = (const float*)d_in[15];

  float* ws    = (float*)d_ws;
  float* h     = ws;                  // MP*128
  float* xn    = ws + 4194304;        // MP*128  (reused as sega during scan)
  float* xm    = ws + 8388608;        // MP*256  (reused as y after conv)
  float* z     = ws + 16777216;       // MP*256
  float* xc    = ws + 25165824;       // MP*256
  float* xdbl  = ws + 33554432;       // MP*40
  float* delta = ws + 34865152;       // MP*256
  float* segh  = ws + 43253760;       // 16*256*16*64 = 4194304
  float* pooled= ws + 47448064;       // 2048
  float* sega  = xn;                  // overlay: xn dead once in_proj GEMMs done
  float* out   = (float*)d_out;

  // encoder: h = x @ enc_w^T + enc_b
  gemm_nt<0><<<dim3(512, 2), 256, 0, stream>>>(x, enc_w, enc_b, h, MP, DM, 12);

  for (int i = 0; i < 4; i++) {
    rmsnorm_kernel<<<MP / 4, 256, 0, stream>>>(h, norm_w + i * DM, xn);
    // in_proj: xm = first 256 rows, z = last 256 rows
    gemm_nt<0><<<dim3(512, 4), 256, 0, stream>>>(xn, in_proj_w + i * 65536,
                                                 nullptr, xm, MP, DI, DM);
    gemm_nt<0><<<dim3(512, 4), 256, 0, stream>>>(xn, in_proj_w + i * 65536 + DI * DM,
                                                 nullptr, z, MP, DI, DM);
    conv_silu_kernel<<<MP, 256, 0, stream>>>(xm, conv_w + i * DI * 4,
                                             conv_b + i * DI, xc);
    gemm_nt<0><<<dim3(512, 1), 256, 0, stream>>>(xc, x_proj_w + i * 40 * DI,
                                                 nullptr, xdbl, MP, 40, DI);
    dtproj_kernel<<<MP, 256, 0, stream>>>(xdbl, dt_proj_w + i * DI * DTR,
                                          dt_proj_b + i * DI, delta);
    scan_phase1<<<dim3(NSEG, BB), 256, 0, stream>>>(delta, xc, xdbl,
                                                    A_log + i * DI * DS, sega, segh);
    scan_combine<<<256, 256, 0, stream>>>(sega, segh);
    scan_phase2<<<dim3(NSEG, BB), 256, 0, stream>>>(delta, xc, xdbl, z,
                                                    A_log + i * DI * DS,
                                                    Dp + i * DI, sega, xm);
    // out_proj accumulated into residual h
    gemm_nt<1><<<dim3(512, 2), 256, 0, stream>>>(xm, out_proj_w + i * DM * DI,
                                                 nullptr, h, MP, DM, DI);
  }

  rmsnorm_kernel<<<MP / 4, 256, 0, stream>>>(h, norm_f_w, xn);
  zero_kernel<<<8, 256, 0, stream>>>(pooled, BB * DM);
  pool_kernel<<<dim3(BB, 8), 256, 0, stream>>>(xn, pooled);
  cls_kernel<<<1, 128, 0, stream>>>(pooled, cls_w, cls_b, out);
}

// Round 2
// 1362.222 us; speedup vs baseline: 1.0585x; 1.0585x over previous
//
#include <hip/hip_runtime.h>
#include <hip/hip_bf16.h>
#include <cstddef>

#define BB 16
#define LL 2048
#define DM 128
#define DI 256
#define DS 16
#define MP (BB*LL)          // 32768 positions
#define NSEG 64
#define SEGLEN (LL/NSEG)    // 32

typedef __attribute__((ext_vector_type(8))) short bf16x8;
typedef __attribute__((ext_vector_type(4))) float f32x4;
typedef __hip_bfloat16 bf16;

__device__ inline void bf16split(float x, bf16& h, bf16& l) {
  h = __float2bfloat16(x);
  l = __float2bfloat16(x - __bfloat162float(h));
}
__device__ inline float bf2f(bf16 v) { return __bfloat162float(v); }

// ---------------------------------------------------------------------------
// Split-precision bf16 MFMA GEMM: C[M,N] (+)= A[M,K] @ W[N,K]^T
// A,W given as hi/lo bf16 pairs. No LDS: fragments load 16B contiguous
// directly from global ([M,K]/[N,K] row-major match the A/B layouts:
// A[m=lane&15][k=quad*8+j], B[k=quad*8+j][n=lane&15]).
// Block 256 = 4 waves (2x2); wave tile 32x32 = 2x2 16x16x32 frags.
// ---------------------------------------------------------------------------
template<int ACCUM>
__global__ __launch_bounds__(256) void gemm_mfma(
    const bf16* __restrict__ Ah, const bf16* __restrict__ Al,
    const bf16* __restrict__ Wh, const bf16* __restrict__ Wl,
    float* __restrict__ C, int M, int N, int K, int ldc) {
  int tid = threadIdx.x;
  int wave = tid >> 6, lane = tid & 63;
  int r16 = lane & 15, quad = lane >> 4;
  int m0 = blockIdx.x * 64 + (wave & 1) * 32;
  int n0 = blockIdx.y * 64 + (wave >> 1) * 32;
  f32x4 acc[2][2] = {};
  for (int k0 = 0; k0 < K; k0 += 32) {
    bf16x8 ah[2], al[2], bh[2], bl[2];
#pragma unroll
    for (int i = 0; i < 2; i++) {
      size_t ao = (size_t)(m0 + i * 16 + r16) * K + k0 + quad * 8;
      ah[i] = *(const bf16x8*)(Ah + ao);
      al[i] = *(const bf16x8*)(Al + ao);
      size_t bo = (size_t)(n0 + i * 16 + r16) * K + k0 + quad * 8;
      bh[i] = *(const bf16x8*)(Wh + bo);
      bl[i] = *(const bf16x8*)(Wl + bo);
    }
#pragma unroll
    for (int i = 0; i < 2; i++)
#pragma unroll
      for (int j = 0; j < 2; j++) {
        acc[i][j] = __builtin_amdgcn_mfma_f32_16x16x32_bf16(ah[i], bh[j], acc[i][j], 0, 0, 0);
        acc[i][j] = __builtin_amdgcn_mfma_f32_16x16x32_bf16(ah[i], bl[j], acc[i][j], 0, 0, 0);
        acc[i][j] = __builtin_amdgcn_mfma_f32_16x16x32_bf16(al[i], bh[j], acc[i][j], 0, 0, 0);
      }
  }
#pragma unroll
  for (int i = 0; i < 2; i++)
#pragma unroll
    for (int j = 0; j < 2; j++)
#pragma unroll
      for (int r = 0; r < 4; r++) {
        int row = m0 + i * 16 + quad * 4 + r;
        int col = n0 + j * 16 + r16;
        if (ACCUM) C[(size_t)row * ldc + col] += acc[i][j][r];
        else       C[(size_t)row * ldc + col] = acc[i][j][r];
      }
}

// ---------------------------------------------------------------------------
// fp32 GEMM for the tiny-K encoder only (K=12).
// ---------------------------------------------------------------------------
__global__ __launch_bounds__(256) void gemm_nt(const float* __restrict__ A,
    const float* __restrict__ W, const float* __restrict__ bias,
    float* __restrict__ C, int M, int N, int K) {
  __shared__ float As[16][68];
  __shared__ float Ws[16][68];
  int tid = threadIdx.x;
  int m0 = blockIdx.x * 64, n0 = blockIdx.y * 64;
  int tx = tid & 15, ty = tid >> 4;
  float acc[4][4] = {};
  for (int k0 = 0; k0 < K; k0 += 16) {
#pragma unroll
    for (int i = 0; i < 4; i++) {
      int idx = tid + i * 256;
      int mm = idx >> 4, kk = idx & 15;
      int gk = k0 + kk;
      int gm = m0 + mm;
      As[kk][mm] = (gk < K && gm < M) ? A[(size_t)gm * K + gk] : 0.f;
      int gn = n0 + mm;
      Ws[kk][mm] = (gk < K && gn < N) ? W[(size_t)gn * K + gk] : 0.f;
    }
    __syncthreads();
#pragma unroll
    for (int kk = 0; kk < 16; kk++) {
      float4 av = *(const float4*)(&As[kk][ty * 4]);
      float4 wv = *(const float4*)(&Ws[kk][tx * 4]);
      float aa[4] = {av.x, av.y, av.z, av.w};
      float ww[4] = {wv.x, wv.y, wv.z, wv.w};
#pragma unroll
      for (int i = 0; i < 4; i++)
#pragma unroll
        for (int j = 0; j < 4; j++)
          acc[i][j] += aa[i] * ww[j];
    }
    __syncthreads();
  }
#pragma unroll
  for (int i = 0; i < 4; i++) {
    int gm = m0 + ty * 4 + i;
#pragma unroll
    for (int j = 0; j < 4; j++) {
      int gn = n0 + tx * 4 + j;
      float v = acc[i][j];
      if (bias) v += bias[gn];
      C[(size_t)gm * N + gn] = v;
    }
  }
}

// ---------------------------------------------------------------------------
// Weight split kernels (fp32 -> hi/lo bf16); run every call.
// ---------------------------------------------------------------------------
__global__ void split_w(const float* __restrict__ src, bf16* __restrict__ hi,
                        bf16* __restrict__ lo, int n) {
  int i = blockIdx.x * 256 + threadIdx.x;
  if (i < n) bf16split(src[i], hi[i], lo[i]);
}

// x_proj [4,40,256] -> padded [4,64,256]
__global__ void split_w_pad(const float* __restrict__ src, bf16* __restrict__ hi,
                            bf16* __restrict__ lo) {
  int i = blockIdx.x * 256 + threadIdx.x;   // < 4*64*256
  int l = i >> 14, rem = i & 16383, r = rem >> 8, k = rem & 255;
  float v = (r < 40) ? src[l * 10240 + r * 256 + k] : 0.f;
  bf16split(v, hi[i], lo[i]);
}

// ---------------------------------------------------------------------------
// RMSNorm (D=128): writes fp32 dump + hi/lo bf16.
// ---------------------------------------------------------------------------
__global__ __launch_bounds__(256) void rmsnorm_kernel(const float* __restrict__ x,
    const float* __restrict__ w, float* __restrict__ of,
    bf16* __restrict__ oh, bf16* __restrict__ ol) {
  int lane = threadIdx.x & 63;
  int pos = blockIdx.x * 4 + (threadIdx.x >> 6);
  const float* row = x + (size_t)pos * DM;
  float v0 = row[lane], v1 = row[lane + 64];
  float ss = v0 * v0 + v1 * v1;
#pragma unroll
  for (int off = 1; off < 64; off <<= 1) ss += __shfl_xor(ss, off);
  float sc = rsqrtf(ss * (1.f / DM) + 1e-5f);
  float a = v0 * sc * w[lane], b = v1 * sc * w[lane + 64];
  size_t o = (size_t)pos * DM;
  of[o + lane] = a; of[o + lane + 64] = b;
  bf16split(a, oh[o + lane], ol[o + lane]);
  bf16split(b, oh[o + lane + 64], ol[o + lane + 64]);
}

// ---------------------------------------------------------------------------
// Causal depthwise conv (k=4) + bias + SiLU; reads xm half of xz [M,512],
// writes hi/lo bf16.
// ---------------------------------------------------------------------------
__global__ __launch_bounds__(256) void conv_silu_kernel(const float* __restrict__ xz,
    const float* __restrict__ cw, const float* __restrict__ cb,
    bf16* __restrict__ oh, bf16* __restrict__ ol) {
  int idx = blockIdx.x * 256 + threadIdx.x;   // pos*256 + d
  int d = idx & 255;
  int pos = idx >> 8;
  int l = pos & (LL - 1);
  size_t src = (size_t)pos * 512 + d;
  float w0 = cw[d * 4], w1 = cw[d * 4 + 1], w2 = cw[d * 4 + 2], w3 = cw[d * 4 + 3];
  float acc = cb[d] + w3 * xz[src];
  if (l > 0) acc += w2 * xz[src - 512];
  if (l > 1) acc += w1 * xz[src - 1024];
  if (l > 2) acc += w0 * xz[src - 1536];
  float s = acc / (1.f + __expf(-acc));
  bf16split(s, oh[idx], ol[idx]);
}

// ---------------------------------------------------------------------------
// Segmented selective scan, delta (dt_proj+softplus) computed on the fly.
// xdbl layout [M,64]: dt 0..7, B 8..23, C 24..39.
// ---------------------------------------------------------------------------
__device__ inline float softplus_f(float a) {
  return fmaxf(a, 0.f) + log1pf(__expf(-fabsf(a)));
}

__global__ __launch_bounds__(256) void scan_phase1(
    const bf16* __restrict__ xc_hi, const bf16* __restrict__ xc_lo,
    const float* __restrict__ xdbl, const float* __restrict__ dtw,
    const float* __restrict__ dtb, const float* __restrict__ A_log,
    float* __restrict__ sega, float* __restrict__ segh) {
  int s = blockIdx.x, b = blockIdx.y, d = threadIdx.x;
  float wdt[8];
#pragma unroll
  for (int j = 0; j < 8; j++) wdt[j] = dtw[d * 8 + j];
  float bdt = dtb[d];
  float Ad[DS], h[DS], ap[DS];
#pragma unroll
  for (int n = 0; n < DS; n++) {
    Ad[n] = -__expf(A_log[d * DS + n]);
    h[n] = 0.f; ap[n] = 1.f;
  }
  size_t base = (size_t)b * LL + s * SEGLEN;
  for (int t = 0; t < SEGLEN; t++) {
    size_t p = base + t;
    const float* xr = xdbl + p * 64;
    float dtacc = bdt;
#pragma unroll
    for (int j = 0; j < 8; j++) dtacc += xr[j] * wdt[j];
    float dl = softplus_f(dtacc);
    float u = bf2f(xc_hi[p * 256 + d]) + bf2f(xc_lo[p * 256 + d]);
    float du = dl * u;
#pragma unroll
    for (int n = 0; n < DS; n++) {
      float dA = __expf(dl * Ad[n]);
      h[n] = dA * h[n] + du * xr[8 + n];
      ap[n] *= dA;
    }
  }
  size_t o = ((size_t)s * 4096 + b * 256 + d) * DS;
#pragma unroll
  for (int n = 0; n < DS; n++) { sega[o + n] = ap[n]; segh[o + n] = h[n]; }
}

__global__ __launch_bounds__(256) void scan_combine(float* __restrict__ sega,
    const float* __restrict__ segh) {
  int idx = blockIdx.x * 256 + threadIdx.x;  // 65536 chains
  float h0 = 0.f;
  for (int s = 0; s < NSEG; s++) {
    size_t q = (size_t)s * 65536 + idx;
    float a = sega[q], hh = segh[q];
    sega[q] = h0;
    h0 = a * h0 + hh;
  }
}

__global__ __launch_bounds__(256) void scan_phase2(
    const bf16* __restrict__ xc_hi, const bf16* __restrict__ xc_lo,
    const float* __restrict__ xdbl, const float* __restrict__ xz,
    const float* __restrict__ dtw, const float* __restrict__ dtb,
    const float* __restrict__ A_log, const float* __restrict__ Dp,
    const float* __restrict__ sega, bf16* __restrict__ y_hi,
    bf16* __restrict__ y_lo) {
  int s = blockIdx.x, b = blockIdx.y, d = threadIdx.x;
  float wdt[8];
#pragma unroll
  for (int j = 0; j < 8; j++) wdt[j] = dtw[d * 8 + j];
  float bdt = dtb[d];
  float Ad[DS], h[DS];
  size_t o = ((size_t)s * 4096 + b * 256 + d) * DS;
#pragma unroll
  for (int n = 0; n < DS; n++) {
    Ad[n] = -__expf(A_log[d * DS + n]);
    h[n] = sega[o + n];
  }
  float Dd = Dp[d];
  size_t base = (size_t)b * LL + s * SEGLEN;
  for (int t = 0; t < SEGLEN; t++) {
    size_t p = base + t;
    const float* xr = xdbl + p * 64;
    float dtacc = bdt;
#pragma unroll
    for (int j = 0; j < 8; j++) dtacc += xr[j] * wdt[j];
    float dl = softplus_f(dtacc);
    float u = bf2f(xc_hi[p * 256 + d]) + bf2f(xc_lo[p * 256 + d]);
    float du = dl * u;
    float acc = 0.f;
#pragma unroll
    for (int n = 0; n < DS; n++) {
      float dA = __expf(dl * Ad[n]);
      h[n] = dA * h[n] + du * xr[8 + n];
      acc += h[n] * xr[24 + n];
    }
    float zv = xz[p * 512 + 256 + d];
    float sig = 1.f / (1.f + __expf(-zv));
    float yv = (acc + u * Dd) * (zv * sig);
    bf16split(yv, y_hi[p * 256 + d], y_lo[p * 256 + d]);
  }
}

// ---------------------------------------------------------------------------
// Final pooling + classifier
// ---------------------------------------------------------------------------
__global__ void zero_kernel(float* __restrict__ p, int n) {
  int i = blockIdx.x * 256 + threadIdx.x;
  if (i < n) p[i] = 0.f;
}

__global__ __launch_bounds__(256) void pool_kernel(const float* __restrict__ xn,
    float* __restrict__ pooled) {
  int b = blockIdx.x, chunk = blockIdx.y;
  int d = threadIdx.x & 127, lh = threadIdx.x >> 7;
  float s = 0.f;
  size_t base = (size_t)b * LL + chunk * 256 + lh * 128;
  for (int i = 0; i < 128; i++) s += xn[(base + i) * DM + d];
  atomicAdd(&pooled[b * DM + d], s * (1.f / LL));
}

__global__ void cls_kernel(const float* __restrict__ pooled,
    const float* __restrict__ cw, const float* __restrict__ cb,
    float* __restrict__ out) {
  int t = threadIdx.x;
  if (t < 80) {
    int b = t / 5, c = t % 5;
    float acc = cb[c];
    for (int d = 0; d < DM; d++) acc += pooled[b * DM + d] * cw[c * DM + d];
    out[t] = acc;
  }
}

// ---------------------------------------------------------------------------
extern "C" void kernel_launch(void* const* d_in, const int* in_sizes, int n_in,
                              void* d_out, int out_size, void* d_ws, size_t ws_size,
                              hipStream_t stream) {
  const float* x         = (const float*)d_in[0];
  const float* enc_w     = (const float*)d_in[1];
  const float* enc_b     = (const float*)d_in[2];
  const float* norm_w    = (const float*)d_in[3];
  const float* in_proj_w = (const float*)d_in[4];
  const float* conv_w    = (const float*)d_in[5];
  const float* conv_b    = (const float*)d_in[6];
  const float* x_proj_w  = (const float*)d_in[7];
  const float* dt_proj_w = (const float*)d_in[8];
  const float* dt_proj_b = (const float*)d_in[9];
  const float* A_log     = (const float*)d_in[10];
  const float* Dp        = (const float*)d_in[11];
  const float* out_proj_w= (const float*)d_in[12];
  const float* norm_f_w  = (const float*)d_in[13];
  const float* cls_w     = (const float*)d_in[14];
  const float* cls_b     = (const float*)d_in[15];
  float* out = (float*)d_out;

  float* ws = (float*)d_ws;
  // fp32 regions (element offsets)
  float* h      = ws;                  // MP*128 = 4194304
  float* xz     = ws + 4194304;        // MP*512 = 16777216
  float* xdbl   = ws + 20971520;       // MP*64  = 2097152
  float* segAUX = ws + 23068672;       // 4194304: rmsnorm f32 dump / segh / y_hi / fnorm
  float* sega   = ws + 27262976;       // 4194304
  float* pooled = ws + 31457280;       // 2048
  // bf16 regions
  bf16* u0     = (bf16*)(ws + 31457792);
  bf16* xn_hi  = u0;                   // MP*128 (region doubles as y_lo)
  bf16* xn_lo  = u0 + 4194304;         // MP*128
  bf16* xc_hi  = u0 + 8388608;         // MP*256
  bf16* xc_lo  = u0 + 16777216;        // MP*256
  bf16* wip_hi = u0 + 25165824;        // 4*512*128 = 262144
  bf16* wip_lo = wip_hi + 262144;
  bf16* wxp_hi = wip_lo + 262144;      // 4*64*256 = 65536 (padded)
  bf16* wxp_lo = wxp_hi + 65536;
  bf16* wop_hi = wxp_lo + 65536;       // 4*128*256 = 131072
  bf16* wop_lo = wop_hi + 131072;
  // overlays
  float* segh  = segAUX;               // scan segment finals
  bf16*  y_hi  = (bf16*)segAUX;        // MP*256 bf16 == 4194304 floats (after combine)
  bf16*  y_lo  = xn_hi;                // xn dead after in_proj GEMM
  float* fnorm = segAUX;               // final rmsnorm output

  // weight splits (every call; no persistent state allowed)
  split_w<<<1024, 256, 0, stream>>>(in_proj_w, wip_hi, wip_lo, 262144);
  split_w_pad<<<256, 256, 0, stream>>>(x_proj_w, wxp_hi, wxp_lo);
  split_w<<<512, 256, 0, stream>>>(out_proj_w, wop_hi, wop_lo, 131072);

  // encoder (fp32, K=12)
  gemm_nt<<<dim3(512, 2), 256, 0, stream>>>(x, enc_w, enc_b, h, MP, DM, 12);

  for (int i = 0; i < 4; i++) {
    rmsnorm_kernel<<<MP / 4, 256, 0, stream>>>(h, norm_w + i * DM, segAUX, xn_hi, xn_lo);
    // in_proj: xz[M,512] = xn @ W^T  (both xm and z halves in one GEMM)
    gemm_mfma<0><<<dim3(512, 8), 256, 0, stream>>>(xn_hi, xn_lo,
        wip_hi + i * 65536, wip_lo + i * 65536, xz, MP, 512, DM, 512);
    conv_silu_kernel<<<MP, 256, 0, stream>>>(xz, conv_w + i * DI * 4,
        conv_b + i * DI, xc_hi, xc_lo);
    // x_proj: xdbl[M,64] = xc @ Wxp^T (N padded 40->64)
    gemm_mfma<0><<<dim3(512, 1), 256, 0, stream>>>(xc_hi, xc_lo,
        wxp_hi + i * 16384, wxp_lo + i * 16384, xdbl, MP, 64, DI, 64);
    scan_phase1<<<dim3(NSEG, BB), 256, 0, stream>>>(xc_hi, xc_lo, xdbl,
        dt_proj_w + i * 2048, dt_proj_b + i * DI, A_log + i * DI * DS, sega, segh);
    scan_combine<<<256, 256, 0, stream>>>(sega, segh);
    scan_phase2<<<dim3(NSEG, BB), 256, 0, stream>>>(xc_hi, xc_lo, xdbl, xz,
        dt_proj_w + i * 2048, dt_proj_b + i * DI, A_log + i * DI * DS,
        Dp + i * DI, sega, y_hi, y_lo);
    // out_proj accumulated into residual h
    gemm_mfma<1><<<dim3(512, 2), 256, 0, stream>>>(y_hi, y_lo,
        wop_hi + i * 32768, wop_lo + i * 32768, h, MP, DM, DI, DM);
  }

  rmsnorm_kernel<<<MP / 4, 256, 0, stream>>>(h, norm_f_w, fnorm, xn_hi, xn_lo);
  zero_kernel<<<8, 256, 0, stream>>>(pooled, BB * DM);
  pool_kernel<<<dim3(BB, 8), 256, 0, stream>>>(fnorm, pooled);
  cls_kernel<<<1, 128, 0, stream>>>(pooled, cls_w, cls_b, out);
}

// Round 3
// 1220.317 us; speedup vs baseline: 1.1816x; 1.1163x over previous
//
#include <hip/hip_runtime.h>
#include <hip/hip_bf16.h>
#include <cstddef>

#define BB 16
#define LL 2048
#define DM 128
#define DI 256
#define DS 16
#define MP (BB*LL)          // 32768 positions
#define NSEG 64
#define SEGLEN (LL/NSEG)    // 32

typedef __attribute__((ext_vector_type(8))) short bf16x8;
typedef __attribute__((ext_vector_type(4))) float f32x4;
typedef __hip_bfloat16 bf16;

__device__ inline void bf16split(float x, bf16& h, bf16& l) {
  h = __float2bfloat16(x);
  l = __float2bfloat16(x - __bfloat162float(h));
}
__device__ inline float bf2f(bf16 v) { return __bfloat162float(v); }

// ---------------------------------------------------------------------------
// Split-precision bf16 MFMA GEMM: C[M,N] (+)= A[M,K] @ W[N,K]^T
// ---------------------------------------------------------------------------
template<int ACCUM>
__global__ __launch_bounds__(256) void gemm_mfma(
    const bf16* __restrict__ Ah, const bf16* __restrict__ Al,
    const bf16* __restrict__ Wh, const bf16* __restrict__ Wl,
    float* __restrict__ C, int M, int N, int K, int ldc) {
  int tid = threadIdx.x;
  int wave = tid >> 6, lane = tid & 63;
  int r16 = lane & 15, quad = lane >> 4;
  int m0 = blockIdx.x * 64 + (wave & 1) * 32;
  int n0 = blockIdx.y * 64 + (wave >> 1) * 32;
  f32x4 acc[2][2] = {};
  for (int k0 = 0; k0 < K; k0 += 32) {
    bf16x8 ah[2], al[2], bh[2], bl[2];
#pragma unroll
    for (int i = 0; i < 2; i++) {
      size_t ao = (size_t)(m0 + i * 16 + r16) * K + k0 + quad * 8;
      ah[i] = *(const bf16x8*)(Ah + ao);
      al[i] = *(const bf16x8*)(Al + ao);
      size_t bo = (size_t)(n0 + i * 16 + r16) * K + k0 + quad * 8;
      bh[i] = *(const bf16x8*)(Wh + bo);
      bl[i] = *(const bf16x8*)(Wl + bo);
    }
#pragma unroll
    for (int i = 0; i < 2; i++)
#pragma unroll
      for (int j = 0; j < 2; j++) {
        acc[i][j] = __builtin_amdgcn_mfma_f32_16x16x32_bf16(ah[i], bh[j], acc[i][j], 0, 0, 0);
        acc[i][j] = __builtin_amdgcn_mfma_f32_16x16x32_bf16(ah[i], bl[j], acc[i][j], 0, 0, 0);
        acc[i][j] = __builtin_amdgcn_mfma_f32_16x16x32_bf16(al[i], bh[j], acc[i][j], 0, 0, 0);
      }
  }
#pragma unroll
  for (int i = 0; i < 2; i++)
#pragma unroll
    for (int j = 0; j < 2; j++)
#pragma unroll
      for (int r = 0; r < 4; r++) {
        int row = m0 + i * 16 + quad * 4 + r;
        int col = n0 + j * 16 + r16;
        if (ACCUM) C[(size_t)row * ldc + col] += acc[i][j][r];
        else       C[(size_t)row * ldc + col] = acc[i][j][r];
      }
}

// ---------------------------------------------------------------------------
// fp32 GEMM for the tiny-K encoder only (K=12).
// ---------------------------------------------------------------------------
__global__ __launch_bounds__(256) void gemm_nt(const float* __restrict__ A,
    const float* __restrict__ W, const float* __restrict__ bias,
    float* __restrict__ C, int M, int N, int K) {
  __shared__ float As[16][68];
  __shared__ float Ws[16][68];
  int tid = threadIdx.x;
  int m0 = blockIdx.x * 64, n0 = blockIdx.y * 64;
  int tx = tid & 15, ty = tid >> 4;
  float acc[4][4] = {};
  for (int k0 = 0; k0 < K; k0 += 16) {
#pragma unroll
    for (int i = 0; i < 4; i++) {
      int idx = tid + i * 256;
      int mm = idx >> 4, kk = idx & 15;
      int gk = k0 + kk;
      int gm = m0 + mm;
      As[kk][mm] = (gk < K && gm < M) ? A[(size_t)gm * K + gk] : 0.f;
      int gn = n0 + mm;
      Ws[kk][mm] = (gk < K && gn < N) ? W[(size_t)gn * K + gk] : 0.f;
    }
    __syncthreads();
#pragma unroll
    for (int kk = 0; kk < 16; kk++) {
      float4 av = *(const float4*)(&As[kk][ty * 4]);
      float4 wv = *(const float4*)(&Ws[kk][tx * 4]);
      float aa[4] = {av.x, av.y, av.z, av.w};
      float ww[4] = {wv.x, wv.y, wv.z, wv.w};
#pragma unroll
      for (int i = 0; i < 4; i++)
#pragma unroll
        for (int j = 0; j < 4; j++)
          acc[i][j] += aa[i] * ww[j];
    }
    __syncthreads();
  }
#pragma unroll
  for (int i = 0; i < 4; i++) {
    int gm = m0 + ty * 4 + i;
#pragma unroll
    for (int j = 0; j < 4; j++) {
      int gn = n0 + tx * 4 + j;
      float v = acc[i][j];
      if (bias) v += bias[gn];
      C[(size_t)gm * N + gn] = v;
    }
  }
}

// ---------------------------------------------------------------------------
// Weight split kernels (fp32 -> hi/lo bf16)
// ---------------------------------------------------------------------------
__global__ void split_w(const float* __restrict__ src, bf16* __restrict__ hi,
                        bf16* __restrict__ lo, int n) {
  int i = blockIdx.x * 256 + threadIdx.x;
  if (i < n) bf16split(src[i], hi[i], lo[i]);
}

__global__ void split_w_pad(const float* __restrict__ src, bf16* __restrict__ hi,
                            bf16* __restrict__ lo) {
  int i = blockIdx.x * 256 + threadIdx.x;   // < 4*64*256
  int l = i >> 14, rem = i & 16383, r = rem >> 8, k = rem & 255;
  float v = (r < 40) ? src[l * 10240 + r * 256 + k] : 0.f;
  bf16split(v, hi[i], lo[i]);
}

// ---------------------------------------------------------------------------
// RMSNorm (D=128). WF32: also dump fp32 (only needed for final norm).
// ---------------------------------------------------------------------------
template<int WF32>
__global__ __launch_bounds__(256) void rmsnorm_kernel(const float* __restrict__ x,
    const float* __restrict__ w, float* __restrict__ of,
    bf16* __restrict__ oh, bf16* __restrict__ ol) {
  int lane = threadIdx.x & 63;
  int pos = blockIdx.x * 4 + (threadIdx.x >> 6);
  const float* row = x + (size_t)pos * DM;
  float v0 = row[lane], v1 = row[lane + 64];
  float ss = v0 * v0 + v1 * v1;
#pragma unroll
  for (int off = 1; off < 64; off <<= 1) ss += __shfl_xor(ss, off);
  float sc = rsqrtf(ss * (1.f / DM) + 1e-5f);
  float a = v0 * sc * w[lane], b = v1 * sc * w[lane + 64];
  size_t o = (size_t)pos * DM;
  if (WF32) { of[o + lane] = a; of[o + lane + 64] = b; }
  bf16split(a, oh[o + lane], ol[o + lane]);
  bf16split(b, oh[o + lane + 64], ol[o + lane + 64]);
}

// ---------------------------------------------------------------------------
// Causal depthwise conv (k=4) + bias + SiLU; reads xm half of xz [M,512].
// ---------------------------------------------------------------------------
__global__ __launch_bounds__(256) void conv_silu_kernel(const float* __restrict__ xz,
    const float* __restrict__ cw, const float* __restrict__ cb,
    bf16* __restrict__ oh, bf16* __restrict__ ol) {
  int idx = blockIdx.x * 256 + threadIdx.x;   // pos*256 + d
  int d = idx & 255;
  int pos = idx >> 8;
  int l = pos & (LL - 1);
  size_t src = (size_t)pos * 512 + d;
  float w0 = cw[d * 4], w1 = cw[d * 4 + 1], w2 = cw[d * 4 + 2], w3 = cw[d * 4 + 3];
  float acc = cb[d] + w3 * xz[src];
  if (l > 0) acc += w2 * xz[src - 512];
  if (l > 1) acc += w1 * xz[src - 1024];
  if (l > 2) acc += w0 * xz[src - 1536];
  float s = acc / (1.f + __expf(-acc));
  bf16split(s, oh[idx], ol[idx]);
}

// ---------------------------------------------------------------------------
// Segmented selective scan.
// FAST path exploits A[d][n] == -(n+1) (true for the given A_log =
// log(arange(1,17)) broadcast): dA[n] = exp(-dl)^(n+1) -> 1 exp + 15 muls,
// and phase1's running product collapses to one scalar R (ap[n]=R^(n+1)).
// Tolerance-checked per thread with a generic fallback loop.
// xdbl layout [M,64]: dt 0..7, B 8..23, C 24..39.
// ---------------------------------------------------------------------------
__device__ inline float softplus_f(float a) {
  return fmaxf(a, 0.f) + log1pf(__expf(-fabsf(a)));
}

__device__ inline void make_powers(float r, float* rp) {
  rp[0] = r;
#pragma unroll
  for (int n = 1; n < 16; n++) {
    int a = (n + 1) >> 1, b = (n + 1) - a;
    rp[n] = rp[a - 1] * rp[b - 1];
  }
}

__device__ inline bool a_is_integer(const float* A_log, int d) {
  bool ok = true;
#pragma unroll
  for (int n = 0; n < DS; n++) {
    float Ad = -__expf(A_log[d * DS + n]);
    ok = ok && (fabsf(Ad + (float)(n + 1)) < 1e-3f);
  }
  return ok;
}

template<bool FAST>
__device__ inline void scan1_body(int s, int b, int d,
    const bf16* __restrict__ xc_hi, const bf16* __restrict__ xc_lo,
    const float* __restrict__ xdbl, const float* __restrict__ dtw,
    const float* __restrict__ dtb, const float* __restrict__ A_log,
    float* __restrict__ sega, float* __restrict__ segh) {
  float wdt[8];
#pragma unroll
  for (int j = 0; j < 8; j++) wdt[j] = dtw[d * 8 + j];
  float bdt = dtb[d];
  float h[DS];
#pragma unroll
  for (int n = 0; n < DS; n++) h[n] = 0.f;
  float R = 1.f;
  float ap[DS];
  if (!FAST) {
#pragma unroll
    for (int n = 0; n < DS; n++) ap[n] = 1.f;
  }
  size_t base = (size_t)b * LL + (size_t)s * SEGLEN;
  for (int t = 0; t < SEGLEN; t++) {
    size_t p = base + t;
    const float* xr = xdbl + p * 64;
    float4 d0 = *(const float4*)xr, d1 = *(const float4*)(xr + 4);
    float4 B0 = *(const float4*)(xr + 8),  float4B1 = *(const float4*)(xr + 12);
    float4 B2 = *(const float4*)(xr + 16), B3 = *(const float4*)(xr + 20);
    float dt = bdt + d0.x*wdt[0] + d0.y*wdt[1] + d0.z*wdt[2] + d0.w*wdt[3]
                   + d1.x*wdt[4] + d1.y*wdt[5] + d1.z*wdt[6] + d1.w*wdt[7];
    float dl = softplus_f(dt);
    float u = bf2f(xc_hi[p * 256 + d]) + bf2f(xc_lo[p * 256 + d]);
    float du = dl * u;
    float Bv[DS] = {B0.x,B0.y,B0.z,B0.w, float4B1.x,float4B1.y,float4B1.z,float4B1.w,
                    B2.x,B2.y,B2.z,B2.w, B3.x,B3.y,B3.z,B3.w};
    if (FAST) {
      float rp[DS];
      make_powers(__expf(-dl), rp);
      R *= rp[0];
#pragma unroll
      for (int n = 0; n < DS; n++) h[n] = fmaf(rp[n], h[n], du * Bv[n]);
    } else {
#pragma unroll
      for (int n = 0; n < DS; n++) {
        float dA = __expf(dl * (-__expf(A_log[d * DS + n])));
        h[n] = fmaf(dA, h[n], du * Bv[n]);
        ap[n] *= dA;
      }
    }
  }
  if (FAST) make_powers(R, ap);
  size_t o = ((size_t)s * 4096 + b * 256 + d) * DS;
#pragma unroll
  for (int n = 0; n < DS; n++) { sega[o + n] = ap[n]; segh[o + n] = h[n]; }
}

__global__ __launch_bounds__(256, 4) void scan_phase1(
    const bf16* __restrict__ xc_hi, const bf16* __restrict__ xc_lo,
    const float* __restrict__ xdbl, const float* __restrict__ dtw,
    const float* __restrict__ dtb, const float* __restrict__ A_log,
    float* __restrict__ sega, float* __restrict__ segh) {
  int s = blockIdx.x, b = blockIdx.y, d = threadIdx.x;
  if (a_is_integer(A_log, d))
    scan1_body<true>(s, b, d, xc_hi, xc_lo, xdbl, dtw, dtb, A_log, sega, segh);
  else
    scan1_body<false>(s, b, d, xc_hi, xc_lo, xdbl, dtw, dtb, A_log, sega, segh);
}

__global__ __launch_bounds__(256) void scan_combine(float* __restrict__ sega,
    const float* __restrict__ segh) {
  int idx = blockIdx.x * 256 + threadIdx.x;  // 65536 chains
  float h0 = 0.f;
  for (int s = 0; s < NSEG; s++) {
    size_t q = (size_t)s * 65536 + idx;
    float a = sega[q], hh = segh[q];
    sega[q] = h0;
    h0 = a * h0 + hh;
  }
}

template<bool FAST>
__device__ inline void scan2_body(int s, int b, int d,
    const bf16* __restrict__ xc_hi, const bf16* __restrict__ xc_lo,
    const float* __restrict__ xdbl, const float* __restrict__ xz,
    const float* __restrict__ dtw, const float* __restrict__ dtb,
    const float* __restrict__ A_log, const float* __restrict__ Dp,
    const float* __restrict__ sega, bf16* __restrict__ y_hi,
    bf16* __restrict__ y_lo) {
  float wdt[8];
#pragma unroll
  for (int j = 0; j < 8; j++) wdt[j] = dtw[d * 8 + j];
  float bdt = dtb[d];
  float h[DS];
  size_t o = ((size_t)s * 4096 + b * 256 + d) * DS;
#pragma unroll
  for (int n = 0; n < DS; n++) h[n] = sega[o + n];
  float Dd = Dp[d];
  size_t base = (size_t)b * LL + (size_t)s * SEGLEN;
  for (int t = 0; t < SEGLEN; t++) {
    size_t p = base + t;
    const float* xr = xdbl + p * 64;
    float4 d0 = *(const float4*)xr, d1 = *(const float4*)(xr + 4);
    float4 B0 = *(const float4*)(xr + 8),  B1 = *(const float4*)(xr + 12);
    float4 B2 = *(const float4*)(xr + 16), B3 = *(const float4*)(xr + 20);
    float4 C0 = *(const float4*)(xr + 24), C1 = *(const float4*)(xr + 28);
    float4 C2 = *(const float4*)(xr + 32), C3 = *(const float4*)(xr + 36);
    float dt = bdt + d0.x*wdt[0] + d0.y*wdt[1] + d0.z*wdt[2] + d0.w*wdt[3]
                   + d1.x*wdt[4] + d1.y*wdt[5] + d1.z*wdt[6] + d1.w*wdt[7];
    float dl = softplus_f(dt);
    float u = bf2f(xc_hi[p * 256 + d]) + bf2f(xc_lo[p * 256 + d]);
    float du = dl * u;
    float Bv[DS] = {B0.x,B0.y,B0.z,B0.w, B1.x,B1.y,B1.z,B1.w,
                    B2.x,B2.y,B2.z,B2.w, B3.x,B3.y,B3.z,B3.w};
    float Cv[DS] = {C0.x,C0.y,C0.z,C0.w, C1.x,C1.y,C1.z,C1.w,
                    C2.x,C2.y,C2.z,C2.w, C3.x,C3.y,C3.z,C3.w};
    float acc = 0.f;
    if (FAST) {
      float rp[DS];
      make_powers(__expf(-dl), rp);
#pragma unroll
      for (int n = 0; n < DS; n++) {
        h[n] = fmaf(rp[n], h[n], du * Bv[n]);
        acc = fmaf(h[n], Cv[n], acc);
      }
    } else {
#pragma unroll
      for (int n = 0; n < DS; n++) {
        float dA = __expf(dl * (-__expf(A_log[d * DS + n])));
        h[n] = fmaf(dA, h[n], du * Bv[n]);
        acc = fmaf(h[n], Cv[n], acc);
      }
    }
    float zv = xz[p * 512 + 256 + d];
    float sig = 1.f / (1.f + __expf(-zv));
    float yv = (acc + u * Dd) * (zv * sig);
    bf16split(yv, y_hi[p * 256 + d], y_lo[p * 256 + d]);
  }
}

__global__ __launch_bounds__(256, 4) void scan_phase2(
    const bf16* __restrict__ xc_hi, const bf16* __restrict__ xc_lo,
    const float* __restrict__ xdbl, const float* __restrict__ xz,
    const float* __restrict__ dtw, const float* __restrict__ dtb,
    const float* __restrict__ A_log, const float* __restrict__ Dp,
    const float* __restrict__ sega, bf16* __restrict__ y_hi,
    bf16* __restrict__ y_lo) {
  int s = blockIdx.x, b = blockIdx.y, d = threadIdx.x;
  if (a_is_integer(A_log, d))
    scan2_body<true>(s, b, d, xc_hi, xc_lo, xdbl, xz, dtw, dtb, A_log, Dp, sega, y_hi, y_lo);
  else
    scan2_body<false>(s, b, d, xc_hi, xc_lo, xdbl, xz, dtw, dtb, A_log, Dp, sega, y_hi, y_lo);
}

// ---------------------------------------------------------------------------
// Final pooling + classifier
// ---------------------------------------------------------------------------
__global__ void zero_kernel(float* __restrict__ p, int n) {
  int i = blockIdx.x * 256 + threadIdx.x;
  if (i < n) p[i] = 0.f;
}

__global__ __launch_bounds__(256) void pool_kernel(const float* __restrict__ xn,
    float* __restrict__ pooled) {
  int b = blockIdx.x, chunk = blockIdx.y;
  int d = threadIdx.x & 127, lh = threadIdx.x >> 7;
  float s = 0.f;
  size_t base = (size_t)b * LL + chunk * 256 + lh * 128;
  for (int i = 0; i < 128; i++) s += xn[(base + i) * DM + d];
  atomicAdd(&pooled[b * DM + d], s * (1.f / LL));
}

__global__ void cls_kernel(const float* __restrict__ pooled,
    const float* __restrict__ cw, const float* __restrict__ cb,
    float* __restrict__ out) {
  int t = threadIdx.x;
  if (t < 80) {
    int b = t / 5, c = t % 5;
    float acc = cb[c];
    for (int d = 0; d < DM; d++) acc += pooled[b * DM + d] * cw[c * DM + d];
    out[t] = acc;
  }
}

// ---------------------------------------------------------------------------
extern "C" void kernel_launch(void* const* d_in, const int* in_sizes, int n_in,
                              void* d_out, int out_size, void* d_ws, size_t ws_size,
                              hipStream_t stream) {
  const float* x         = (const float*)d_in[0];
  const float* enc_w     = (const float*)d_in[1];
  const float* enc_b     = (const float*)d_in[2];
  const float* norm_w    = (const float*)d_in[3];
  const float* in_proj_w = (const float*)d_in[4];
  const float* conv_w    = (const float*)d_in[5];
  const float* conv_b    = (const float*)d_in[6];
  const float* x_proj_w  = (const float*)d_in[7];
  const float* dt_proj_w = (const float*)d_in[8];
  const float* dt_proj_b = (const float*)d_in[9];
  const float* A_log     = (const float*)d_in[10];
  const float* Dp        = (const float*)d_in[11];
  const float* out_proj_w= (const float*)d_in[12];
  const float* norm_f_w  = (const float*)d_in[13];
  const float* cls_w     = (const float*)d_in[14];
  const float* cls_b     = (const float*)d_in[15];
  float* out = (float*)d_out;

  float* ws = (float*)d_ws;
  float* h      = ws;                  // MP*128 = 4194304
  float* xz     = ws + 4194304;        // MP*512 = 16777216
  float* xdbl   = ws + 20971520;       // MP*64  = 2097152
  float* segAUX = ws + 23068672;       // 4194304: segh / y_hi / fnorm
  float* sega   = ws + 27262976;       // 4194304
  float* pooled = ws + 31457280;       // 2048
  bf16* u0     = (bf16*)(ws + 31457792);
  bf16* xn_hi  = u0;                   // MP*128
  bf16* xn_lo  = u0 + 4194304;         // MP*128
  bf16* xc_hi  = u0 + 8388608;         // MP*256
  bf16* xc_lo  = u0 + 16777216;        // MP*256
  bf16* wip_hi = u0 + 25165824;        // 4*512*128
  bf16* wip_lo = wip_hi + 262144;
  bf16* wxp_hi = wip_lo + 262144;      // 4*64*256 (padded)
  bf16* wxp_lo = wxp_hi + 65536;
  bf16* wop_hi = wxp_lo + 65536;       // 4*128*256
  bf16* wop_lo = wop_hi + 131072;
  float* segh  = segAUX;
  bf16*  y_hi  = (bf16*)segAUX;        // after combine, segh dead
  bf16*  y_lo  = xn_hi;                // xn dead after in_proj GEMM
  float* fnorm = segAUX;

  split_w<<<1024, 256, 0, stream>>>(in_proj_w, wip_hi, wip_lo, 262144);
  split_w_pad<<<256, 256, 0, stream>>>(x_proj_w, wxp_hi, wxp_lo);
  split_w<<<512, 256, 0, stream>>>(out_proj_w, wop_hi, wop_lo, 131072);

  gemm_nt<<<dim3(512, 2), 256, 0, stream>>>(x, enc_w, enc_b, h, MP, DM, 12);

  for (int i = 0; i < 4; i++) {
    rmsnorm_kernel<0><<<MP / 4, 256, 0, stream>>>(h, norm_w + i * DM, nullptr, xn_hi, xn_lo);
    gemm_mfma<0><<<dim3(512, 8), 256, 0, stream>>>(xn_hi, xn_lo,
        wip_hi + i * 65536, wip_lo + i * 65536, xz, MP, 512, DM, 512);
    conv_silu_kernel<<<MP, 256, 0, stream>>>(xz, conv_w + i * DI * 4,
        conv_b + i * DI, xc_hi, xc_lo);
    gemm_mfma<0><<<dim3(512, 1), 256, 0, stream>>>(xc_hi, xc_lo,
        wxp_hi + i * 16384, wxp_lo + i * 16384, xdbl, MP, 64, DI, 64);
    scan_phase1<<<dim3(NSEG, BB), 256, 0, stream>>>(xc_hi, xc_lo, xdbl,
        dt_proj_w + i * 2048, dt_proj_b + i * DI, A_log + i * DI * DS, sega, segh);
    scan_combine<<<256, 256, 0, stream>>>(sega, segh);
    scan_phase2<<<dim3(NSEG, BB), 256, 0, stream>>>(xc_hi, xc_lo, xdbl, xz,
        dt_proj_w + i * 2048, dt_proj_b + i * DI, A_log + i * DI * DS,
        Dp + i * DI, sega, y_hi, y_lo);
    gemm_mfma<1><<<dim3(512, 2), 256, 0, stream>>>(y_hi, y_lo,
        wop_hi + i * 32768, wop_lo + i * 32768, h, MP, DM, DI, DM);
  }

  rmsnorm_kernel<1><<<MP / 4, 256, 0, stream>>>(h, norm_f_w, fnorm, xn_hi, xn_lo);
  zero_kernel<<<8, 256, 0, stream>>>(pooled, BB * DM);
  pool_kernel<<<dim3(BB, 8), 256, 0, stream>>>(fnorm, pooled);
  cls_kernel<<<1, 128, 0, stream>>>(pooled, cls_w, cls_b, out);
}

// Round 4
// 1122.205 us; speedup vs baseline: 1.2849x; 1.0874x over previous
//
#include <hip/hip_runtime.h>
#include <hip/hip_bf16.h>
#include <cstddef>

#define BB 16
#define LL 2048
#define DM 128
#define DI 256
#define DS 16
#define MP (BB*LL)          // 32768 positions
#define NSEG 128
#define SEGLEN (LL/NSEG)    // 16

typedef __attribute__((ext_vector_type(8))) short bf16x8;
typedef __attribute__((ext_vector_type(4))) float f32x4;
typedef __hip_bfloat16 bf16;

__device__ inline void bf16split(float x, bf16& h, bf16& l) {
  h = __float2bfloat16(x);
  l = __float2bfloat16(x - __bfloat162float(h));
}
__device__ inline float bf2f(bf16 v) { return __bfloat162float(v); }

// ---------------------------------------------------------------------------
// Split-precision bf16 MFMA GEMM: C[M,N] (+)= A[M,K] @ W[N,K]^T
// K compile-time; fragments for up to 4 K-steps preloaded (32 loads in
// flight, single wait) to kill per-iteration latency serialization.
// ---------------------------------------------------------------------------
template<int ACCUM, int KT>
__global__ __launch_bounds__(256, 2) void gemm_mfma(
    const bf16* __restrict__ Ah, const bf16* __restrict__ Al,
    const bf16* __restrict__ Wh, const bf16* __restrict__ Wl,
    float* __restrict__ C, int ldc) {
  constexpr int NK = KT / 32;
  constexpr int CH = NK < 4 ? NK : 4;
  int tid = threadIdx.x;
  int wave = tid >> 6, lane = tid & 63;
  int r16 = lane & 15, quad = lane >> 4;
  int m0 = blockIdx.x * 64 + (wave & 1) * 32;
  int n0 = blockIdx.y * 64 + (wave >> 1) * 32;
  size_t arow[2], brow[2];
#pragma unroll
  for (int i = 0; i < 2; i++) {
    arow[i] = (size_t)(m0 + i * 16 + r16) * KT + quad * 8;
    brow[i] = (size_t)(n0 + i * 16 + r16) * KT + quad * 8;
  }
  f32x4 acc[2][2] = {};
#pragma unroll
  for (int c = 0; c < NK / CH; c++) {
    bf16x8 ah[2][CH], al[2][CH], bh[2][CH], bl[2][CH];
#pragma unroll
    for (int kk = 0; kk < CH; kk++) {
      int ko = (c * CH + kk) * 32;
#pragma unroll
      for (int i = 0; i < 2; i++) {
        ah[i][kk] = *(const bf16x8*)(Ah + arow[i] + ko);
        al[i][kk] = *(const bf16x8*)(Al + arow[i] + ko);
        bh[i][kk] = *(const bf16x8*)(Wh + brow[i] + ko);
        bl[i][kk] = *(const bf16x8*)(Wl + brow[i] + ko);
      }
    }
#pragma unroll
    for (int kk = 0; kk < CH; kk++)
#pragma unroll
      for (int i = 0; i < 2; i++)
#pragma unroll
        for (int j = 0; j < 2; j++) {
          acc[i][j] = __builtin_amdgcn_mfma_f32_16x16x32_bf16(ah[i][kk], bh[j][kk], acc[i][j], 0, 0, 0);
          acc[i][j] = __builtin_amdgcn_mfma_f32_16x16x32_bf16(ah[i][kk], bl[j][kk], acc[i][j], 0, 0, 0);
          acc[i][j] = __builtin_amdgcn_mfma_f32_16x16x32_bf16(al[i][kk], bh[j][kk], acc[i][j], 0, 0, 0);
        }
  }
#pragma unroll
  for (int i = 0; i < 2; i++)
#pragma unroll
    for (int j = 0; j < 2; j++)
#pragma unroll
      for (int r = 0; r < 4; r++) {
        int row = m0 + i * 16 + quad * 4 + r;
        int col = n0 + j * 16 + r16;
        if (ACCUM) C[(size_t)row * ldc + col] += acc[i][j][r];
        else       C[(size_t)row * ldc + col] = acc[i][j][r];
      }
}

// ---------------------------------------------------------------------------
// Encoder: h[m,d] = sum_c x[m,c]*enc_w[d,c] + enc_b[d]   (K=12, direct)
// ---------------------------------------------------------------------------
__global__ __launch_bounds__(256) void encoder_kernel(const float* __restrict__ x,
    const float* __restrict__ ew, const float* __restrict__ eb,
    float* __restrict__ h) {
  int idx = blockIdx.x * 256 + threadIdx.x;   // m*128 + d
  int d = idx & 127, m = idx >> 7;
  float acc = eb[d];
#pragma unroll
  for (int c = 0; c < 12; c++) acc += x[m * 12 + c] * ew[d * 12 + c];
  h[idx] = acc;
}

// ---------------------------------------------------------------------------
// Weight split kernels (fp32 -> hi/lo bf16)
// ---------------------------------------------------------------------------
__global__ void split_w(const float* __restrict__ src, bf16* __restrict__ hi,
                        bf16* __restrict__ lo, int n) {
  int i = blockIdx.x * 256 + threadIdx.x;
  if (i < n) bf16split(src[i], hi[i], lo[i]);
}

__global__ void split_w_pad(const float* __restrict__ src, bf16* __restrict__ hi,
                            bf16* __restrict__ lo) {
  int i = blockIdx.x * 256 + threadIdx.x;   // < 4*64*256
  int l = i >> 14, rem = i & 16383, r = rem >> 8, k = rem & 255;
  float v = (r < 40) ? src[l * 10240 + r * 256 + k] : 0.f;
  bf16split(v, hi[i], lo[i]);
}

// ---------------------------------------------------------------------------
// RMSNorm (D=128). WF32: also dump fp32 (final norm only).
// ---------------------------------------------------------------------------
template<int WF32>
__global__ __launch_bounds__(256) void rmsnorm_kernel(const float* __restrict__ x,
    const float* __restrict__ w, float* __restrict__ of,
    bf16* __restrict__ oh, bf16* __restrict__ ol) {
  int lane = threadIdx.x & 63;
  int pos = blockIdx.x * 4 + (threadIdx.x >> 6);
  const float* row = x + (size_t)pos * DM;
  float v0 = row[lane], v1 = row[lane + 64];
  float ss = v0 * v0 + v1 * v1;
#pragma unroll
  for (int off = 1; off < 64; off <<= 1) ss += __shfl_xor(ss, off);
  float sc = rsqrtf(ss * (1.f / DM) + 1e-5f);
  float a = v0 * sc * w[lane], b = v1 * sc * w[lane + 64];
  size_t o = (size_t)pos * DM;
  if (WF32) { of[o + lane] = a; of[o + lane + 64] = b; }
  bf16split(a, oh[o + lane], ol[o + lane]);
  bf16split(b, oh[o + lane + 64], ol[o + lane + 64]);
}

// ---------------------------------------------------------------------------
// Causal depthwise conv (k=4) + bias + SiLU. Sliding-window registers:
// block = 16-position chunk x 256 d; 1 load per position.
// ---------------------------------------------------------------------------
__global__ __launch_bounds__(256) void conv_silu_kernel(const float* __restrict__ xz,
    const float* __restrict__ cw, const float* __restrict__ cb,
    bf16* __restrict__ oh, bf16* __restrict__ ol) {
  int d = threadIdx.x;
  int pos0 = blockIdx.x * 16;
  int l0 = pos0 & (LL - 1);
  float w0 = cw[d * 4], w1 = cw[d * 4 + 1], w2 = cw[d * 4 + 2], w3 = cw[d * 4 + 3];
  float bias = cb[d];
  float x0 = 0.f, x1 = 0.f, x2 = 0.f;
  if (l0 > 0) {  // chunk not at sequence start -> all 3 predecessors exist
    x2 = xz[(size_t)(pos0 - 1) * 512 + d];
    x1 = xz[(size_t)(pos0 - 2) * 512 + d];
    x0 = xz[(size_t)(pos0 - 3) * 512 + d];
  }
#pragma unroll
  for (int t = 0; t < 16; t++) {
    int pos = pos0 + t;
    float x3 = xz[(size_t)pos * 512 + d];
    float acc = bias + w0 * x0 + w1 * x1 + w2 * x2 + w3 * x3;
    float s = acc / (1.f + __expf(-acc));
    bf16split(s, oh[(size_t)pos * 256 + d], ol[(size_t)pos * 256 + d]);
    x0 = x1; x1 = x2; x2 = x3;
  }
}

// ---------------------------------------------------------------------------
// Segmented selective scan. xdbl rows staged in LDS once per segment.
// FAST path exploits A[d][n] == -(n+1): dA[n] = exp(-dl)^(n+1).
// ---------------------------------------------------------------------------
__device__ inline float softplus_f(float a) {
  return fmaxf(a, 0.f) + log1pf(__expf(-fabsf(a)));
}

__device__ inline void make_powers(float r, float* rp) {
  rp[0] = r;
#pragma unroll
  for (int n = 1; n < 16; n++) {
    int a = (n + 1) >> 1, b = (n + 1) - a;
    rp[n] = rp[a - 1] * rp[b - 1];
  }
}

__device__ inline bool a_is_integer(const float* A_log, int d) {
  bool ok = true;
#pragma unroll
  for (int n = 0; n < DS; n++) {
    float Ad = -__expf(A_log[d * DS + n]);
    ok = ok && (fabsf(Ad + (float)(n + 1)) < 1e-3f);
  }
  return ok;
}

template<bool FAST>
__device__ inline void scan1_body(int s, int b, int d, const float* sx,
    const bf16* __restrict__ xc_hi, const bf16* __restrict__ xc_lo,
    const float* __restrict__ dtw, const float* __restrict__ dtb,
    const float* __restrict__ A_log,
    float* __restrict__ sega, float* __restrict__ segh) {
  float wdt[8];
#pragma unroll
  for (int j = 0; j < 8; j++) wdt[j] = dtw[d * 8 + j];
  float bdt = dtb[d];
  float h[DS];
#pragma unroll
  for (int n = 0; n < DS; n++) h[n] = 0.f;
  float R = 1.f;
  float ap[DS];
  if (!FAST) {
#pragma unroll
    for (int n = 0; n < DS; n++) ap[n] = 1.f;
  }
  size_t base = (size_t)b * LL + (size_t)s * SEGLEN;
#pragma unroll
  for (int t = 0; t < SEGLEN; t++) {
    size_t p = base + t;
    const float* xr = sx + t * 64;
    float dt = bdt;
#pragma unroll
    for (int j = 0; j < 8; j++) dt += xr[j] * wdt[j];
    float dl = softplus_f(dt);
    float u = bf2f(xc_hi[p * 256 + d]) + bf2f(xc_lo[p * 256 + d]);
    float du = dl * u;
    if (FAST) {
      float rp[DS];
      make_powers(__expf(-dl), rp);
      R *= rp[0];
#pragma unroll
      for (int n = 0; n < DS; n++) h[n] = fmaf(rp[n], h[n], du * xr[8 + n]);
    } else {
#pragma unroll
      for (int n = 0; n < DS; n++) {
        float dA = __expf(dl * (-__expf(A_log[d * DS + n])));
        h[n] = fmaf(dA, h[n], du * xr[8 + n]);
        ap[n] *= dA;
      }
    }
  }
  if (FAST) make_powers(R, ap);
  size_t o = ((size_t)s * 4096 + b * 256 + d) * DS;
#pragma unroll
  for (int j = 0; j < 4; j++) {
    *(float4*)(sega + o + 4 * j) = make_float4(ap[4*j], ap[4*j+1], ap[4*j+2], ap[4*j+3]);
    *(float4*)(segh + o + 4 * j) = make_float4(h[4*j], h[4*j+1], h[4*j+2], h[4*j+3]);
  }
}

__global__ __launch_bounds__(256, 2) void scan_phase1(
    const bf16* __restrict__ xc_hi, const bf16* __restrict__ xc_lo,
    const float* __restrict__ xdbl, const float* __restrict__ dtw,
    const float* __restrict__ dtb, const float* __restrict__ A_log,
    float* __restrict__ sega, float* __restrict__ segh) {
  __shared__ float sx[SEGLEN * 64];
  int s = blockIdx.x, b = blockIdx.y, d = threadIdx.x;
  size_t rbase = ((size_t)b * LL + (size_t)s * SEGLEN) * 64;
  *(float4*)(sx + d * 4) = *(const float4*)(xdbl + rbase + d * 4);
  __syncthreads();
  if (a_is_integer(A_log, d))
    scan1_body<true>(s, b, d, sx, xc_hi, xc_lo, dtw, dtb, A_log, sega, segh);
  else
    scan1_body<false>(s, b, d, sx, xc_hi, xc_lo, dtw, dtb, A_log, sega, segh);
}

__global__ __launch_bounds__(256) void scan_combine(float* __restrict__ sega,
    const float* __restrict__ segh) {
  int idx = blockIdx.x * 256 + threadIdx.x;  // 65536 chains
  float h0 = 0.f;
  for (int s = 0; s < NSEG; s++) {
    size_t q = (size_t)s * 65536 + idx;
    float a = sega[q], hh = segh[q];
    sega[q] = h0;
    h0 = a * h0 + hh;
  }
}

template<bool FAST>
__device__ inline void scan2_body(int s, int b, int d, const float* sx,
    const bf16* __restrict__ xc_hi, const bf16* __restrict__ xc_lo,
    const float* __restrict__ xz, const float* __restrict__ dtw,
    const float* __restrict__ dtb, const float* __restrict__ A_log,
    const float* __restrict__ Dp, const float* __restrict__ sega,
    bf16* __restrict__ y_hi, bf16* __restrict__ y_lo) {
  float wdt[8];
#pragma unroll
  for (int j = 0; j < 8; j++) wdt[j] = dtw[d * 8 + j];
  float bdt = dtb[d];
  float h[DS];
  size_t o = ((size_t)s * 4096 + b * 256 + d) * DS;
#pragma unroll
  for (int n = 0; n < DS; n++) h[n] = sega[o + n];
  float Dd = Dp[d];
  size_t base = (size_t)b * LL + (size_t)s * SEGLEN;
#pragma unroll
  for (int t = 0; t < SEGLEN; t++) {
    size_t p = base + t;
    const float* xr = sx + t * 64;
    float dt = bdt;
#pragma unroll
    for (int j = 0; j < 8; j++) dt += xr[j] * wdt[j];
    float dl = softplus_f(dt);
    float u = bf2f(xc_hi[p * 256 + d]) + bf2f(xc_lo[p * 256 + d]);
    float du = dl * u;
    float acc = 0.f;
    if (FAST) {
      float rp[DS];
      make_powers(__expf(-dl), rp);
#pragma unroll
      for (int n = 0; n < DS; n++) {
        h[n] = fmaf(rp[n], h[n], du * xr[8 + n]);
        acc = fmaf(h[n], xr[24 + n], acc);
      }
    } else {
#pragma unroll
      for (int n = 0; n < DS; n++) {
        float dA = __expf(dl * (-__expf(A_log[d * DS + n])));
        h[n] = fmaf(dA, h[n], du * xr[8 + n]);
        acc = fmaf(h[n], xr[24 + n], acc);
      }
    }
    float zv = xz[p * 512 + 256 + d];
    float sig = 1.f / (1.f + __expf(-zv));
    float yv = (acc + u * Dd) * (zv * sig);
    bf16split(yv, y_hi[p * 256 + d], y_lo[p * 256 + d]);
  }
}

__global__ __launch_bounds__(256, 2) void scan_phase2(
    const bf16* __restrict__ xc_hi, const bf16* __restrict__ xc_lo,
    const float* __restrict__ xdbl, const float* __restrict__ xz,
    const float* __restrict__ dtw, const float* __restrict__ dtb,
    const float* __restrict__ A_log, const float* __restrict__ Dp,
    const float* __restrict__ sega, bf16* __restrict__ y_hi,
    bf16* __restrict__ y_lo) {
  __shared__ float sx[SEGLEN * 64];
  int s = blockIdx.x, b = blockIdx.y, d = threadIdx.x;
  size_t rbase = ((size_t)b * LL + (size_t)s * SEGLEN) * 64;
  *(float4*)(sx + d * 4) = *(const float4*)(xdbl + rbase + d * 4);
  __syncthreads();
  if (a_is_integer(A_log, d))
    scan2_body<true>(s, b, d, sx, xc_hi, xc_lo, xz, dtw, dtb, A_log, Dp, sega, y_hi, y_lo);
  else
    scan2_body<false>(s, b, d, sx, xc_hi, xc_lo, xz, dtw, dtb, A_log, Dp, sega, y_hi, y_lo);
}

// ---------------------------------------------------------------------------
// Final pooling + classifier
// ---------------------------------------------------------------------------
__global__ void zero_kernel(float* __restrict__ p, int n) {
  int i = blockIdx.x * 256 + threadIdx.x;
  if (i < n) p[i] = 0.f;
}

__global__ __launch_bounds__(256) void pool_kernel(const float* __restrict__ xn,
    float* __restrict__ pooled) {
  int b = blockIdx.x, chunk = blockIdx.y;
  int d = threadIdx.x & 127, lh = threadIdx.x >> 7;
  float s = 0.f;
  size_t base = (size_t)b * LL + chunk * 256 + lh * 128;
  for (int i = 0; i < 128; i++) s += xn[(base + i) * DM + d];
  atomicAdd(&pooled[b * DM + d], s * (1.f / LL));
}

__global__ void cls_kernel(const float* __restrict__ pooled,
    const float* __restrict__ cw, const float* __restrict__ cb,
    float* __restrict__ out) {
  int t = threadIdx.x;
  if (t < 80) {
    int b = t / 5, c = t % 5;
    float acc = cb[c];
    for (int d = 0; d < DM; d++) acc += pooled[b * DM + d] * cw[c * DM + d];
    out[t] = acc;
  }
}

// ---------------------------------------------------------------------------
extern "C" void kernel_launch(void* const* d_in, const int* in_sizes, int n_in,
                              void* d_out, int out_size, void* d_ws, size_t ws_size,
                              hipStream_t stream) {
  const float* x         = (const float*)d_in[0];
  const float* enc_w     = (const float*)d_in[1];
  const float* enc_b     = (const float*)d_in[2];
  const float* norm_w    = (const float*)d_in[3];
  const float* in_proj_w = (const float*)d_in[4];
  const float* conv_w    = (const float*)d_in[5];
  const float* conv_b    = (const float*)d_in[6];
  const float* x_proj_w  = (const float*)d_in[7];
  const float* dt_proj_w = (const float*)d_in[8];
  const float* dt_proj_b = (const float*)d_in[9];
  const float* A_log     = (const float*)d_in[10];
  const float* Dp        = (const float*)d_in[11];
  const float* out_proj_w= (const float*)d_in[12];
  const float* norm_f_w  = (const float*)d_in[13];
  const float* cls_w     = (const float*)d_in[14];
  const float* cls_b     = (const float*)d_in[15];
  float* out = (float*)d_out;

  float* ws = (float*)d_ws;
  float* h      = ws;                  // 4,194,304
  float* xz     = ws + 4194304;        // 16,777,216
  float* xdbl   = ws + 20971520;       // 2,097,152
  float* sega   = ws + 23068672;       // 8,388,608
  float* segh   = ws + 31457280;       // 8,388,608
  float* pooled = ws + 39845888;       // 2048
  bf16* u0     = (bf16*)(ws + 39847936);
  bf16* xn_hi  = u0;                   // MP*128
  bf16* xn_lo  = u0 + 4194304;         // MP*128
  bf16* xc_hi  = u0 + 8388608;         // MP*256
  bf16* xc_lo  = u0 + 16777216;        // MP*256
  bf16* wip_hi = u0 + 25165824;        // 262144
  bf16* wip_lo = wip_hi + 262144;
  bf16* wxp_hi = wip_lo + 262144;      // 65536 (padded)
  bf16* wxp_lo = wxp_hi + 65536;
  bf16* wop_hi = wxp_lo + 65536;       // 131072
  bf16* wop_lo = wop_hi + 131072;
  // overlays
  bf16*  y_hi  = (bf16*)segh;          // segh dead after combine
  bf16*  y_lo  = xn_hi;                // xn (hi+lo region) dead after in_proj
  float* fnorm = sega;                 // sega dead after last phase2

  split_w<<<1024, 256, 0, stream>>>(in_proj_w, wip_hi, wip_lo, 262144);
  split_w_pad<<<256, 256, 0, stream>>>(x_proj_w, wxp_hi, wxp_lo);
  split_w<<<512, 256, 0, stream>>>(out_proj_w, wop_hi, wop_lo, 131072);

  encoder_kernel<<<MP * DM / 256, 256, 0, stream>>>(x, enc_w, enc_b, h);

  for (int i = 0; i < 4; i++) {
    rmsnorm_kernel<0><<<MP / 4, 256, 0, stream>>>(h, norm_w + i * DM, nullptr, xn_hi, xn_lo);
    gemm_mfma<0, 128><<<dim3(512, 8), 256, 0, stream>>>(xn_hi, xn_lo,
        wip_hi + i * 65536, wip_lo + i * 65536, xz, 512);
    conv_silu_kernel<<<MP / 16, 256, 0, stream>>>(xz, conv_w + i * DI * 4,
        conv_b + i * DI, xc_hi, xc_lo);
    gemm_mfma<0, 256><<<dim3(512, 1), 256, 0, stream>>>(xc_hi, xc_lo,
        wxp_hi + i * 16384, wxp_lo + i * 16384, xdbl, 64);
    scan_phase1<<<dim3(NSEG, BB), 256, 0, stream>>>(xc_hi, xc_lo, xdbl,
        dt_proj_w + i * 2048, dt_proj_b + i * DI, A_log + i * DI * DS, sega, segh);
    scan_combine<<<256, 256, 0, stream>>>(sega, segh);
    scan_phase2<<<dim3(NSEG, BB), 256, 0, stream>>>(xc_hi, xc_lo, xdbl, xz,
        dt_proj_w + i * 2048, dt_proj_b + i * DI, A_log + i * DI * DS,
        Dp + i * DI, sega, y_hi, y_lo);
    gemm_mfma<1, 256><<<dim3(512, 2), 256, 0, stream>>>(y_hi, y_lo,
        wop_hi + i * 32768, wop_lo + i * 32768, h, 128);
  }

  rmsnorm_kernel<1><<<MP / 4, 256, 0, stream>>>(h, norm_f_w, fnorm, xn_hi, xn_lo);
  zero_kernel<<<8, 256, 0, stream>>>(pooled, BB * DM);
  pool_kernel<<<dim3(BB, 8), 256, 0, stream>>>(fnorm, pooled);
  cls_kernel<<<1, 128, 0, stream>>>(pooled, cls_w, cls_b, out);
}